// Round 10
// baseline (134.178 us; speedup 1.0000x reference)
//
#include <hip/hip_runtime.h>

// ACELoss3D round 20: R19 body (champ 116.7us) + 64-line atomic partials.
// Decomposition: fills ~83us (harness-fixed, 81% HBM peak = their roofline),
// main ~28us (latency/ramp bound; instruction-side levers exhausted: R16
// algebra -2.5, R17 pk-fp32 neutral, R19 DPP ~-0.5), final ~4.5us = 1 block
// reading 6144 strided floats written across all 8 XCDs (launch + cross-die
// latency). This round: main's tid0 atomicAdds its block scalar onto one of
// 64 ws lines (blk&63; 96 adds/line ~0.84us, fire-and-forget, lines parallel
// across L2 channels — R15 proved the spread cheap; its regression was the
// counter-chain WAIT, removed here). ace_final becomes ONE 64-lane wave
// reading 64 floats -> near-pure launch latency (~2.5us).
// History: R10 119.7; R11 coop no-op under graph capture; R12 agent fences
// 518; R13 1-addr atomics +55; R14 125.5; R15 counter chain 128.2; R16
// exact-algebra 117.2; R17 pk-fp32 118.5 (fp32 peak = scalar rate on gfx950);
// R18 non-ICE dpp ctrl; R19 DPP z-halo+reduce 116.7 CHAMP.

static constexpr int   NTOT   = 6 * 128 * 128 * 128;   // 12,582,912
static constexpr int   NBLK   = 6144;                  // 32x32 xy-tiles * 6 bc
static constexpr float ALPHA_ = 0.001f;
static constexpr float EPS_   = 1e-8f;

// ---- DPP helpers (all VALU; no DS pipe, no lgkmcnt) ----
template <int CTRL>
__device__ __forceinline__ float dpp_mov(float x) {
  return __int_as_float(__builtin_amdgcn_update_dpp(
      0, __float_as_int(x), CTRL, 0xf, 0xf, true));   // invalid lanes -> 0
}
__device__ __forceinline__ float dpp_up1(float x) {   // == __shfl_up(x,1)
  return dpp_mov<0x138>(x);                           // wave_shr:1
}
__device__ __forceinline__ float dpp_dn1(float x) {   // == __shfl_down(x,1)
  return dpp_mov<0x130>(x);                           // wave_shl:1
}
// Full wave64 sum in 6 VALU adds; total broadcast via readlane 63.
__device__ __forceinline__ float wave_sum(float v) {
  v += dpp_mov<0x111>(v);   // row_shr:1
  v += dpp_mov<0x112>(v);   // row_shr:2
  v += dpp_mov<0x114>(v);   // row_shr:4
  v += dpp_mov<0x118>(v);   // row_shr:8  -> lane 15/31/47/63 = row sums
  v += dpp_mov<0x142>(v);   // row_bcast:15 -> lane 31/63 = half sums
  v += dpp_mov<0x143>(v);   // row_bcast:31 -> lane 63 = wave sum
  return __int_as_float(
      __builtin_amdgcn_readlane(__float_as_int(v), 63));
}

// One output element. di/dj = un-halved first diffs (sign-free, R16); sx/sy =
// uxp+uxm, uyp+uym; dik/djk/dij = un-halved mixed double-diffs.
// 2*cik*cjk*cij = 0.25*dik*djk*dij. Region: t*(t-2u)+u (exact, R16-verified).
__device__ __forceinline__ void elem(
    float uzm, float u0, float uzp,
    float di, float sx, float dj, float sy,
    float dik, float djk, float dij,
    float t, float& s12, float& s3) {
  const float dk  = uzp - uzm;
  const float ci2 = 0.25f * di * di;
  const float cj2 = 0.25f * dj * dj;
  const float ck2 = 0.25f * dk * dk;
  const float u2  = u0 + u0;
  const float cii = sx - u2;
  const float cjj = sy - u2;
  const float ckk = (uzp + uzm) - u2;
  const float ss  = ci2 + cj2 + ck2;
  const float ss1 = 1.f + ss;
  const float L = (cii + cjj) + ckk;
  const float M = fmaf(ci2, cii, fmaf(cj2, cjj, ck2 * ckk));
  float curv = fmaf(ss1, L, -M);
  curv = fmaf(-0.25f * dij, dik * djk, curv);
  const float len = __builtin_amdgcn_sqrtf(EPS_ + ss);
  s3 = fmaf(curv * curv, len * __builtin_amdgcn_rcpf(ss1), s3);
  s12 += fmaf(t, fmaf(-2.f, u0, t), u0);    // u(t-1)^2+(1-u)t^2
}

__global__ __launch_bounds__(512, 4) void ace_main(
    const float* __restrict__ pred, const float* __restrict__ truth,
    float* __restrict__ lines) {
  const int tid = threadIdx.x;
  // Block -> (bc, y-tile, x-tile); thread -> (x-sub, y-sub, z-group).
  const int rem = blockIdx.x & 1023;        // 32x32 xy tiles
  const int bc  = blockIdx.x >> 10;         // 0..5
  const int x   = ((rem & 31) << 2)  + (tid >> 7);
  const int y   = ((rem >> 5) << 2)  + ((tid >> 5) & 3);
  const int z0  = (tid & 31) << 2;                         // 0,4,...,124
  const size_t base = ((size_t)bc) << 21;
  const float* __restrict__ bp = pred + base;

  // Wave halves: lanes 0-31 = even y-sub, lanes 32-63 = odd y-sub (adjacent y).
  const bool upper = (tid & 32) != 0;
  const int yOut = upper ? ((y < 127) ? y + 1 : 127) : ((y > 0) ? y - 1 : 0);
  const int rO  = yOut << 7;
  const int rC  = y << 7;
  const int pC  = x << 14;
  const int pXp = ((x < 127) ? x + 1 : 127) << 14;
  const int pXm = ((x > 0)   ? x - 1 : 0)   << 14;

  // 7 float4 loads — all pinned in flight before any consumer.
  const float4 vC  = *(const float4*)(bp + pC  + rC + z0);
  const float4 vXP = *(const float4*)(bp + pXp + rC + z0);
  const float4 vXM = *(const float4*)(bp + pXm + rC + z0);
  const float4 vOY = *(const float4*)(bp + pC  + rO + z0);   // outward y row
  const float4 vOP = *(const float4*)(bp + pXp + rO + z0);
  const float4 vOM = *(const float4*)(bp + pXm + rO + z0);
  const float4 t4  = *(const float4*)(truth + base + pC + rC + z0);
#if defined(__has_builtin)
#if __has_builtin(__builtin_amdgcn_sched_barrier)
  __builtin_amdgcn_sched_barrier(0);   // keep all 7 loads issued before math
#endif
#endif

  // Center-row x combines.
  const float dxa = vXP.x - vXM.x, dxb = vXP.y - vXM.y;
  const float dxc = vXP.z - vXM.z, dxd = vXP.w - vXM.w;
  const float sxa = vXP.x + vXM.x, sxb = vXP.y + vXM.y;
  const float sxc = vXP.z + vXM.z, sxd = vXP.w + vXM.w;
  // Outward-row x-diff.
  const float dOa = vOP.x - vOM.x, dOb = vOP.y - vOM.y;
  const float dOc = vOP.z - vOM.z, dOd = vOP.w - vOM.w;

  // Inward y-neighbor via half-wave exchange (partner row is never clamped).
  const float iCa = __shfl_xor(vC.x, 32), iCb = __shfl_xor(vC.y, 32);
  const float iCc = __shfl_xor(vC.z, 32), iCd = __shfl_xor(vC.w, 32);
  const float iDa = __shfl_xor(dxa, 32),  iDb = __shfl_xor(dxb, 32);
  const float iDc = __shfl_xor(dxc, 32),  iDd = __shfl_xor(dxd, 32);

  // y combines — sign-free (R16: sgn^2=1 in dij*djk; dj only as dj^2/sy).
  const float sya = iCa + vOY.x, syb = iCb + vOY.y;
  const float syc = iCc + vOY.z, syd = iCd + vOY.w;
  const float dya = vOY.x - iCa, dyb = vOY.y - iCb;
  const float dyc = vOY.z - iCc, dyd = vOY.w - iCd;
  const float ja  = dOa - iDa,   jb  = dOb - iDb;
  const float jc  = dOc - iDc,   jd  = dOd - iDd;

  // z-halo via DPP wave shifts (VALU; invalid + cross-row lanes are exactly
  // the zlo/zhi select-overridden lanes).
  const bool zlo = (z0 == 0), zhi = (z0 == 124);
  float clo  = dpp_up1(vC.w);  clo  = zlo ? vC.x : clo;
  float chi  = dpp_dn1(vC.x);  chi  = zhi ? vC.w : chi;
  float dxm1 = dpp_up1(dxd);   dxm1 = zlo ? dxa : dxm1;
  float dxp4 = dpp_dn1(dxa);   dxp4 = zhi ? dxd : dxp4;
  float dym1 = dpp_up1(dyd);   dym1 = zlo ? dya : dym1;
  float dyp4 = dpp_dn1(dya);   dyp4 = zhi ? dyd : dyp4;

  float s12 = 0.f, s3 = 0.f;
  elem(clo,  vC.x, vC.y, dxa, sxa, dya, sya, dxb - dxm1, dyb - dym1, ja, t4.x, s12, s3);
  elem(vC.x, vC.y, vC.z, dxb, sxb, dyb, syb, dxc - dxa,  dyc - dya,  jb, t4.y, s12, s3);
  elem(vC.y, vC.z, vC.w, dxc, sxc, dyc, syc, dxd - dxb,  dyd - dyb,  jc, t4.z, s12, s3);
  elem(vC.z, vC.w, chi,  dxd, sxd, dyd, syd, dxp4 - dxc, dyp4 - dyc, jd, t4.w, s12, s3);

  // Single scalar per thread; DPP wave sum (6 VALU adds, no DS chain).
  const float wsum = wave_sum(s12 + s3);
  __shared__ float l[8];
  const int lane = tid & 63, wv = tid >> 6;
  if (lane == 0) l[wv] = wsum;
  __syncthreads();
  if (tid == 0) {
    float p = 0.f;
#pragma unroll
    for (int w = 0; w < 8; ++w) p += l[w];
    // Fire-and-forget onto 1 of 64 lines (96 adds/line ~0.84us, lines run in
    // parallel across L2 channels; no fence, no wait — R12/R15 lessons).
    atomicAdd(&lines[blockIdx.x & 63], p);
  }
}

__global__ __launch_bounds__(64) void ace_final(
    const float* __restrict__ lines, float* __restrict__ out) {
  // One wave: read 64 floats, sum, store. Near-pure launch latency.
  const float v = lines[threadIdx.x];
  const float S = wave_sum(v);
  if (threadIdx.x == 0) out[0] = S + ALPHA_ * (float)NTOT;
}

extern "C" void kernel_launch(void* const* d_in, const int* in_sizes, int n_in,
                              void* d_out, int out_size, void* d_ws, size_t ws_size,
                              hipStream_t stream) {
  const float* pred  = (const float*)d_in[0];   // y_pred
  const float* truth = (const float*)d_in[1];   // y_true
  float* out   = (float*)d_out;
  float* lines = (float*)d_ws;                  // 64 f32 accumulator lines

  hipMemsetAsync(lines, 0, 64 * sizeof(float), stream);  // zero the lines
  ace_main<<<NBLK, 512, 0, stream>>>(pred, truth, lines);
  ace_final<<<1, 64, 0, stream>>>(lines, out);
}

// Round 11
// 118.794 us; speedup vs baseline: 1.1295x; 1.1295x over previous
//
#include <hip/hip_runtime.h>

// ACELoss3D round 21: REVERT to R19 champion (116.7us), R20 post-mortem in
// header. R20's "64-line" atomic spread packed all lines into 256B = two
// 128B cache lines -> all 6144 RMWs serialized on 1-2 lines (+16us main).
// Rule (3rd confirmation: R13/R15/R20): atomic-RMW epilogues lose to
// fire-and-forget plain stores + tiny final dispatch on CDNA4.
// Structure: 6144 blocks (4x4x128 tile, 512thr), wave-internal y-exchange
// (shfl_xor 32), DPP z-halo + DPP wave reduce, 1 partial store/block,
// 1-block final reduce. Exact-algebra epilogue (R16): sgn^2=1 cancel,
// region = t(t-2u)+u, single scalar.
// Accounting: fills 2x41.5=83us (harness-fixed, 81% HBM peak = their
// roofline); main ~28us (VALU ~18us @64%, mem floor ~13us, ramp/latency
// rest; 6 levers tried, best -2.5us); final+gaps ~5us (launch latency).
// History: R10 119.7; R11 coop no-op; R12 agent fences 518; R13 1-addr
// atomics 175; R14 125.5; R15 counter chain 128.2; R16 algebra 117.2;
// R17 pk-fp32 118.5 (fp32 peak = scalar rate); R18 dpp-ICE fail; R19 DPP
// 116.7 CHAMP; R20 packed-line atomics 134.2.

static constexpr int   NTOT   = 6 * 128 * 128 * 128;   // 12,582,912
static constexpr int   NBLK   = 6144;                  // 32x32 xy-tiles * 6 bc
static constexpr float ALPHA_ = 0.001f;
static constexpr float EPS_   = 1e-8f;

// ---- DPP helpers (all VALU; no DS pipe, no lgkmcnt) ----
template <int CTRL>
__device__ __forceinline__ float dpp_mov(float x) {
  return __int_as_float(__builtin_amdgcn_update_dpp(
      0, __float_as_int(x), CTRL, 0xf, 0xf, true));   // invalid lanes -> 0
}
__device__ __forceinline__ float dpp_up1(float x) {   // == __shfl_up(x,1)
  return dpp_mov<0x138>(x);                           // wave_shr:1
}
__device__ __forceinline__ float dpp_dn1(float x) {   // == __shfl_down(x,1)
  return dpp_mov<0x130>(x);                           // wave_shl:1
}
// Full wave64 sum in 6 VALU adds; total broadcast via readlane 63.
__device__ __forceinline__ float wave_sum(float v) {
  v += dpp_mov<0x111>(v);   // row_shr:1
  v += dpp_mov<0x112>(v);   // row_shr:2
  v += dpp_mov<0x114>(v);   // row_shr:4
  v += dpp_mov<0x118>(v);   // row_shr:8  -> lane 15/31/47/63 = row sums
  v += dpp_mov<0x142>(v);   // row_bcast:15 -> lane 31/63 = half sums
  v += dpp_mov<0x143>(v);   // row_bcast:31 -> lane 63 = wave sum
  return __int_as_float(
      __builtin_amdgcn_readlane(__float_as_int(v), 63));
}

// One output element. di/dj = un-halved first diffs (sign-free, R16); sx/sy =
// uxp+uxm, uyp+uym; dik/djk/dij = un-halved mixed double-diffs.
// 2*cik*cjk*cij = 0.25*dik*djk*dij. Region: t*(t-2u)+u (exact, R16-verified).
__device__ __forceinline__ void elem(
    float uzm, float u0, float uzp,
    float di, float sx, float dj, float sy,
    float dik, float djk, float dij,
    float t, float& s12, float& s3) {
  const float dk  = uzp - uzm;
  const float ci2 = 0.25f * di * di;
  const float cj2 = 0.25f * dj * dj;
  const float ck2 = 0.25f * dk * dk;
  const float u2  = u0 + u0;
  const float cii = sx - u2;
  const float cjj = sy - u2;
  const float ckk = (uzp + uzm) - u2;
  const float ss  = ci2 + cj2 + ck2;
  const float ss1 = 1.f + ss;
  const float L = (cii + cjj) + ckk;
  const float M = fmaf(ci2, cii, fmaf(cj2, cjj, ck2 * ckk));
  float curv = fmaf(ss1, L, -M);
  curv = fmaf(-0.25f * dij, dik * djk, curv);
  const float len = __builtin_amdgcn_sqrtf(EPS_ + ss);
  s3 = fmaf(curv * curv, len * __builtin_amdgcn_rcpf(ss1), s3);
  s12 += fmaf(t, fmaf(-2.f, u0, t), u0);    // u(t-1)^2+(1-u)t^2
}

__global__ __launch_bounds__(512, 4) void ace_main(
    const float* __restrict__ pred, const float* __restrict__ truth,
    float* __restrict__ partials) {
  const int tid = threadIdx.x;
  // Block -> (bc, y-tile, x-tile); thread -> (x-sub, y-sub, z-group).
  const int rem = blockIdx.x & 1023;        // 32x32 xy tiles
  const int bc  = blockIdx.x >> 10;         // 0..5
  const int x   = ((rem & 31) << 2)  + (tid >> 7);
  const int y   = ((rem >> 5) << 2)  + ((tid >> 5) & 3);
  const int z0  = (tid & 31) << 2;                         // 0,4,...,124
  const size_t base = ((size_t)bc) << 21;
  const float* __restrict__ bp = pred + base;

  // Wave halves: lanes 0-31 = even y-sub, lanes 32-63 = odd y-sub (adjacent y).
  const bool upper = (tid & 32) != 0;
  const int yOut = upper ? ((y < 127) ? y + 1 : 127) : ((y > 0) ? y - 1 : 0);
  const int rO  = yOut << 7;
  const int rC  = y << 7;
  const int pC  = x << 14;
  const int pXp = ((x < 127) ? x + 1 : 127) << 14;
  const int pXm = ((x > 0)   ? x - 1 : 0)   << 14;

  // 7 float4 loads — all pinned in flight before any consumer.
  const float4 vC  = *(const float4*)(bp + pC  + rC + z0);
  const float4 vXP = *(const float4*)(bp + pXp + rC + z0);
  const float4 vXM = *(const float4*)(bp + pXm + rC + z0);
  const float4 vOY = *(const float4*)(bp + pC  + rO + z0);   // outward y row
  const float4 vOP = *(const float4*)(bp + pXp + rO + z0);
  const float4 vOM = *(const float4*)(bp + pXm + rO + z0);
  const float4 t4  = *(const float4*)(truth + base + pC + rC + z0);
#if defined(__has_builtin)
#if __has_builtin(__builtin_amdgcn_sched_barrier)
  __builtin_amdgcn_sched_barrier(0);   // keep all 7 loads issued before math
#endif
#endif

  // Center-row x combines.
  const float dxa = vXP.x - vXM.x, dxb = vXP.y - vXM.y;
  const float dxc = vXP.z - vXM.z, dxd = vXP.w - vXM.w;
  const float sxa = vXP.x + vXM.x, sxb = vXP.y + vXM.y;
  const float sxc = vXP.z + vXM.z, sxd = vXP.w + vXM.w;
  // Outward-row x-diff.
  const float dOa = vOP.x - vOM.x, dOb = vOP.y - vOM.y;
  const float dOc = vOP.z - vOM.z, dOd = vOP.w - vOM.w;

  // Inward y-neighbor via half-wave exchange (partner row is never clamped).
  const float iCa = __shfl_xor(vC.x, 32), iCb = __shfl_xor(vC.y, 32);
  const float iCc = __shfl_xor(vC.z, 32), iCd = __shfl_xor(vC.w, 32);
  const float iDa = __shfl_xor(dxa, 32),  iDb = __shfl_xor(dxb, 32);
  const float iDc = __shfl_xor(dxc, 32),  iDd = __shfl_xor(dxd, 32);

  // y combines — sign-free (R16: sgn^2=1 in dij*djk; dj only as dj^2/sy).
  const float sya = iCa + vOY.x, syb = iCb + vOY.y;
  const float syc = iCc + vOY.z, syd = iCd + vOY.w;
  const float dya = vOY.x - iCa, dyb = vOY.y - iCb;
  const float dyc = vOY.z - iCc, dyd = vOY.w - iCd;
  const float ja  = dOa - iDa,   jb  = dOb - iDb;
  const float jc  = dOc - iDc,   jd  = dOd - iDd;

  // z-halo via DPP wave shifts (VALU; invalid + cross-row lanes are exactly
  // the zlo/zhi select-overridden lanes).
  const bool zlo = (z0 == 0), zhi = (z0 == 124);
  float clo  = dpp_up1(vC.w);  clo  = zlo ? vC.x : clo;
  float chi  = dpp_dn1(vC.x);  chi  = zhi ? vC.w : chi;
  float dxm1 = dpp_up1(dxd);   dxm1 = zlo ? dxa : dxm1;
  float dxp4 = dpp_dn1(dxa);   dxp4 = zhi ? dxd : dxp4;
  float dym1 = dpp_up1(dyd);   dym1 = zlo ? dya : dym1;
  float dyp4 = dpp_dn1(dya);   dyp4 = zhi ? dyd : dyp4;

  float s12 = 0.f, s3 = 0.f;
  elem(clo,  vC.x, vC.y, dxa, sxa, dya, sya, dxb - dxm1, dyb - dym1, ja, t4.x, s12, s3);
  elem(vC.x, vC.y, vC.z, dxb, sxb, dyb, syb, dxc - dxa,  dyc - dya,  jb, t4.y, s12, s3);
  elem(vC.y, vC.z, vC.w, dxc, sxc, dyc, syc, dxd - dxb,  dyd - dyb,  jc, t4.z, s12, s3);
  elem(vC.z, vC.w, chi,  dxd, sxd, dyd, syd, dxp4 - dxc, dyp4 - dyc, jd, t4.w, s12, s3);

  // Single scalar per thread; DPP wave sum (6 VALU adds, no DS chain).
  const float wsum = wave_sum(s12 + s3);
  __shared__ float l[8];
  const int lane = tid & 63, wv = tid >> 6;
  if (lane == 0) l[wv] = wsum;
  __syncthreads();
  if (tid == 0) {
    float p = 0.f;
#pragma unroll
    for (int w = 0; w < 8; ++w) p += l[w];
    partials[blockIdx.x] = p;   // fire-and-forget plain store (the rule)
  }
}

__global__ __launch_bounds__(1024) void ace_final(
    const float* __restrict__ partials, float* __restrict__ out) {
  const int tid = threadIdx.x;
  float s = 0.f;
  const float4* p4 = (const float4*)partials;   // 6144 floats = 1536 float4
#pragma unroll
  for (int i = tid; i < NBLK / 4; i += 1024) {
    const float4 a = p4[i];
    s += (a.x + a.y) + (a.z + a.w);
  }
  const float wsum = wave_sum(s);
  __shared__ float l[16];
  const int lane = tid & 63, wv = tid >> 6;
  if (lane == 0) l[wv] = wsum;
  __syncthreads();
  if (tid == 0) {
    float S = 0.f;
#pragma unroll
    for (int w = 0; w < 16; ++w) S += l[w];
    out[0] = S + ALPHA_ * (float)NTOT;
  }
}

extern "C" void kernel_launch(void* const* d_in, const int* in_sizes, int n_in,
                              void* d_out, int out_size, void* d_ws, size_t ws_size,
                              hipStream_t stream) {
  const float* pred  = (const float*)d_in[0];   // y_pred
  const float* truth = (const float*)d_in[1];   // y_true
  float* out      = (float*)d_out;
  float* partials = (float*)d_ws;               // NBLK floats = 24.6 KB

  ace_main<<<NBLK, 512, 0, stream>>>(pred, truth, partials);
  ace_final<<<1, 1024, 0, stream>>>(partials, out);
}